// Round 21
// baseline (132.825 us; speedup 1.0000x reference)
//
#include <hip/hip_runtime.h>
#include <hip/hip_bf16.h>
#include <stdint.h>

// MHA fwd: B=2, N=2048, D=1024, H=16, HD=64, scale=0.125
#define B_ 2
#define N_ 2048
#define D_ 1024
#define H_ 16
#define SCALE_L2E 0.18033688011112042f  // 0.125 * log2(e): softmax in base-2 domain

typedef unsigned short u16;
typedef unsigned int u32;
using f32x4  = __attribute__((ext_vector_type(4))) float;
using f32x16 = __attribute__((ext_vector_type(16))) float;
using bf16x8 = __attribute__((ext_vector_type(8))) short;
using i16x8  = __attribute__((ext_vector_type(8))) short;

__device__ __forceinline__ u16 f2b(float f) {
  unsigned u = __float_as_uint(f);
  return (u16)((u + 0x7FFFu + ((u >> 16) & 1u)) >> 16);
}
// HW packed f32->bf16 (RNE), inline asm (no builtin on gfx950)
__device__ __forceinline__ u32 pk2(float lo, float hi) {
  u32 r;
  asm("v_cvt_pk_bf16_f32 %0, %1, %2" : "=v"(r) : "v"(lo), "v"(hi));
  return r;
}
__device__ __forceinline__ float ex2(float x) {
  return __builtin_amdgcn_exp2f(x);   // bare v_exp_f32; args bounded here
}
__device__ __forceinline__ void async16(const u16* g, u16* l) {
  __builtin_amdgcn_global_load_lds(
      (const __attribute__((address_space(1))) void*)g,
      (__attribute__((address_space(3))) void*)l, 16, 0, 0);
}
// full compiler fence: IR-level (memory clobber) + machine-scheduler
__device__ __forceinline__ void cfence() {
  asm volatile("" ::: "memory");
  __builtin_amdgcn_sched_barrier(0);
}

// one launch: cast x (4M elems) + Wq,Wk,Wv,Wo (4x1M elems) to bf16
__global__ __launch_bounds__(256) void cast_all(
    const float* __restrict__ x, const float* __restrict__ w0,
    const float* __restrict__ w1, const float* __restrict__ w2,
    const float* __restrict__ w3, u16* __restrict__ xb, u16* __restrict__ Wb) {
  const int i = (blockIdx.x * 256 + threadIdx.x) * 8;
  const float* s;
  u16* d;
  if (i < 4194304) { s = x + i; d = xb + i; }
  else {
    const int j = i - 4194304;
    const int wsel = j >> 20;
    const float* w = wsel == 0 ? w0 : wsel == 1 ? w1 : wsel == 2 ? w2 : w3;
    s = w + (j & 1048575);
    d = Wb + j;
  }
  union { u32 u[4]; i16x8 v; } o;
#pragma unroll
  for (int j = 0; j < 4; ++j) o.u[j] = pk2(s[2 * j], s[2 * j + 1]);
  *(i16x8*)d = o.v;
}

// C = A * Bt^T. 128x128 tile, BK=64, 4 waves (2x2 of 64x64), 32 MFMA/barrier.
// Both-sides chunk-XOR swizzle (pre-swizzled global source + swizzled read)
// -> conflict-free ds_read_b128. Accumulation order identical to BK=32.
// F32OUT==0: merged QKV GEMM — Bt is [3072][1024] (Wq;Wk;Wv); zsel = tN>>10;
// zsel==0 scaled by SCALE_L2E. F32OUT==1: fp32 out + bias.
template <int F32OUT>
__global__ __launch_bounds__(256) void gemm_bt(
    const u16* __restrict__ A, const u16* __restrict__ Bt,
    void* __restrict__ C0, size_t sCz, const float* __restrict__ bias,
    int M, int Nn, int K) {
  __shared__ __align__(16) u16 As[128 * 64];  // 16 KB, chunk-swizzled
  __shared__ __align__(16) u16 Bs[128 * 64];  // 16 KB, chunk-swizzled
  const int tid = threadIdx.x;
  const int w = tid >> 6, l = tid & 63;
  const int wm = w >> 1, wn = w & 1;
  const int la = l & 15, lb = l >> 4;
  const int tM = blockIdx.y * 128, tN = blockIdx.x * 128;

  const int srow8 = l >> 3;                    // 0..7 within an 8-row stripe
  const int scol  = ((l & 7) ^ srow8) << 3;    // pre-swizzled source chunk
  const u16* gA = A + (size_t)(tM + w * 32 + srow8) * K + scol;
  const u16* gB = Bt + (size_t)(tN + w * 32 + srow8) * K + scol;
  u16* lA = As + w * 2048;
  u16* lB = Bs + w * 2048;

  f32x4 acc[4][4] = {};

  for (int k0 = 0; k0 < K; k0 += 64) {
#pragma unroll
    for (int c = 0; c < 4; ++c)
      async16(gA + (size_t)(c * 8) * K, lA + c * 512);
#pragma unroll
    for (int c = 0; c < 4; ++c)
      async16(gB + (size_t)(c * 8) * K, lB + c * 512);
    gA += 64; gB += 64;
    __syncthreads();   // drains vmcnt: tiles resident
    bf16x8 af[4][2], bfr[4][2];
#pragma unroll
    for (int i = 0; i < 4; ++i) {
      const int row = wm * 64 + i * 16 + la;
#pragma unroll
      for (int kk = 0; kk < 2; ++kk)
        af[i][kk] = *(const bf16x8*)(As + row * 64 + (((kk * 4 + lb) ^ (row & 7)) << 3));
    }
#pragma unroll
    for (int j = 0; j < 4; ++j) {
      const int row = wn * 64 + j * 16 + la;
#pragma unroll
      for (int kk = 0; kk < 2; ++kk)
        bfr[j][kk] = *(const bf16x8*)(Bs + row * 64 + (((kk * 4 + lb) ^ (row & 7)) << 3));
    }
#pragma unroll
    for (int kk = 0; kk < 2; ++kk)
#pragma unroll
      for (int i = 0; i < 4; ++i)
#pragma unroll
        for (int j = 0; j < 4; ++j)
          acc[i][j] = __builtin_amdgcn_mfma_f32_16x16x32_bf16(
              af[i][kk], bfr[j][kk], acc[i][j], 0, 0, 0);
    __syncthreads();   // before next stage overwrites
  }

  const int zsel = F32OUT ? 0 : (tN >> 10);
  const int tNl = F32OUT ? tN : (tN & 1023);
  const float osc = (!F32OUT && zsel == 0) ? SCALE_L2E : 1.0f;
  const int ld = F32OUT ? Nn : 1024;
#pragma unroll
  for (int i = 0; i < 4; ++i) {
    const int row = tM + wm * 64 + i * 16 + lb * 4;
#pragma unroll
    for (int j = 0; j < 4; ++j) {
      const int col = tNl + wn * 64 + j * 16 + la;
#pragma unroll
      for (int r = 0; r < 4; ++r) {
        const float v = acc[i][j][r];
        if (F32OUT) {
          ((float*)C0)[(size_t)(row + r) * ld + col] = v + bias[col];
        } else {
          (((u16*)C0) + (size_t)zsel * sCz)[(size_t)(row + r) * ld + col] = f2b(v * osc);
        }
      }
    }
  }
}

// V [B*N][D] (per-head cols) -> VtG [(b*16+h)*64 + d][N]
__global__ __launch_bounds__(256) void vtrans(const u16* __restrict__ V,
                                              u16* __restrict__ Vt) {
  __shared__ u16 T[64][72];
  const int tid = threadIdx.x;
  const int rt = blockIdx.x, h = blockIdx.y;
  const int r = tid >> 3, c = (tid & 7) * 8;
#pragma unroll
  for (int p = 0; p < 2; ++p) {
    i16x8 v = *(const i16x8*)(V + (size_t)(rt * 64 + p * 32 + r) * D_ + h * 64 + c);
#pragma unroll
    for (int j = 0; j < 8; ++j) T[p * 32 + r][c + j] = (u16)v[j];
  }
  __syncthreads();
  const int b = rt >> 5, nb = (rt & 31) * 64;
#pragma unroll
  for (int p = 0; p < 2; ++p) {
    const int d = p * 32 + r;
    i16x8 o;
#pragma unroll
    for (int j = 0; j < 8; ++j) o[j] = (short)T[c + j][d];
    *(i16x8*)(Vt + ((size_t)((b * 16 + h) * 64 + d)) * (size_t)N_ + nb + c) = o;
  }
}

// Flash attention, NSPLIT=1, swapped-QK^T 32x32, static softmax, key-permuted
// K staging, ones-MFMA row-sum, XCD remap.
// NEW (T15): 2-deep P-pipeline — iteration u computes QK^T(u+1)->pb (pure
// MFMA, independent) BEFORE exp2/pack/PV of pa=S(u), so next-tile MFMAs
// execute under this tile's VALU work. Staging split: stageK(u+2) at
// barrier-1 (Ks[buf u] free: QK^T(u) done pre-barrier); stageV(u+2) after
// barrier-2 (Vs[buf u] free after PV(u)). Ledger (2K+2V loads/wave/tile):
// steady outstanding at wait = [V(u),K(u+1),V(u+1)] -> vmcnt(2) drains
// exactly V(u)+K(u+1). Prologue vmcnt(6); last iter vmcnt(0).
__global__ __launch_bounds__(256) void attn_fused(
    const u16* __restrict__ Q, const u16* __restrict__ Kb,
    const u16* __restrict__ VtG, u16* __restrict__ O) {
  __shared__ __align__(16) u16 Ks[2 * 64 * 64];
  __shared__ __align__(16) u16 Vs[2 * 64 * 64];
  const int tid = threadIdx.x;
  const int w = tid >> 6, l = tid & 63;
  const int q = l & 31, hi = l >> 5;

  const int flat = blockIdx.x + 16 * blockIdx.y;
  const int logical = (flat & 7) * 64 + (flat >> 3);
  const int qx = logical & 15;
  const int y  = logical >> 4;

  const int b = y >> 4, h = y & 15;
  const int q0 = qx * 128 + w * 32;

  const u16* Qrow = Q + (size_t)(b * N_ + q0 + q) * D_ + h * 64;
  bf16x8 qf[4];
#pragma unroll
  for (int s = 0; s < 4; ++s) qf[s] = *(const bf16x8*)(Qrow + s * 16 + hi * 8);

  const int srow = l >> 3;
  const int scol = ((l & 7) ^ srow) << 3;
  const int kprow = w * 16 + (srow & 3) + ((srow & 4) << 1);  // key perm (bits 2<->3)
  const u16* Kg = Kb + (size_t)(b * N_ + kprow) * D_ + h * 64 + scol;
  const u16* Vg = VtG + (size_t)(y * 64 + w * 16 + srow) * N_ + scol;

  const int qsw = (q & 7) << 3;
  const int qr0 = q * 64, qr1 = (32 + q) * 64;

  union { u32 u[4]; bf16x8 v; } ones;
#pragma unroll
  for (int j = 0; j < 4; ++j) ones.u[j] = 0x3F803F80u;

  f32x16 o0 = {}, o1 = {}, o_l = {};
  const int NT = N_ / 64;  // 32

  // 2 VMEM ops per stageK / stageV (ledger depends on this)
  auto stageK = [&](int t, int buf) {
    const u16* kg = Kg + (size_t)(t * 64) * D_;
    u16* kd = Ks + buf * 4096 + w * 1024;
    async16(kg, kd);
    async16(kg + (size_t)4 * D_, kd + 512);
  };
  auto stageV = [&](int t, int buf) {
    const u16* vg = Vg + t * 64;
    u16* vd = Vs + buf * 4096 + w * 1024;
    async16(vg, vd);
    async16(vg + (size_t)8 * N_, vd + 512);
  };
  auto qkt = [&](int u, f32x16& n0, f32x16& n1) {
    const u16* KT = Ks + (u & 1) * 4096;
#pragma unroll
    for (int r = 0; r < 16; ++r) { n0[r] = 0.f; n1[r] = 0.f; }
    __builtin_amdgcn_s_setprio(1);
#pragma unroll
    for (int s = 0; s < 4; ++s) {
      const int off = (s * 16 + hi * 8) ^ qsw;
      bf16x8 kf0 = *(const bf16x8*)(KT + qr0 + off);
      bf16x8 kf1 = *(const bf16x8*)(KT + qr1 + off);
      n0 = __builtin_amdgcn_mfma_f32_32x32x16_bf16(kf0, qf[s], n0, 0, 0, 0);
      n1 = __builtin_amdgcn_mfma_f32_32x32x16_bf16(kf1, qf[s], n1, 0, 0, 0);
    }
    __builtin_amdgcn_s_setprio(0);
  };

  // body(u): finish S(u) in (c0,c1); prefetch-compute S(u+1) into (n0,n1)
  auto body = [&](int u, f32x16& c0, f32x16& c1, f32x16& n0, f32x16& n1) {
    if (u + 1 < NT) asm volatile("s_waitcnt vmcnt(2)" ::: "memory");
    else            asm volatile("s_waitcnt vmcnt(0)" ::: "memory");
    __builtin_amdgcn_s_barrier();   // V(u) + K(u+1) resident for all waves
    cfence();
    if (u + 2 < NT) stageK(u + 2, u & 1);  // Ks[buf u]: QK^T(u) done pre-barrier
    if (u + 1 < NT) qkt(u + 1, n0, n1);    // MFMA; executes under VALU below
    // static softmax on current tile
#pragma unroll
    for (int r = 0; r < 16; ++r) c0[r] = ex2(c0[r]);
#pragma unroll
    for (int r = 0; r < 16; ++r) c1[r] = ex2(c1[r]);
    // O^T += V^T P^T ; l += 1^T P^T (own-register B-frags via key perm)
    const u16* VT = Vs + (u & 1) * 4096;
    __builtin_amdgcn_s_setprio(1);
#pragma unroll
    for (int ks = 0; ks < 4; ++ks) {
      const f32x16& P = (ks < 2) ? c0 : c1;
      const int rbq = (ks & 1) * 8;
      union { u32 u4[4]; bf16x8 v; } pb;
#pragma unroll
      for (int j = 0; j < 4; ++j) pb.u4[j] = pk2(P[rbq + 2 * j], P[rbq + 2 * j + 1]);
      const int off = (ks * 16 + hi * 8) ^ qsw;
      bf16x8 va0 = *(const bf16x8*)(VT + qr0 + off);
      bf16x8 va1 = *(const bf16x8*)(VT + qr1 + off);
      o0  = __builtin_amdgcn_mfma_f32_32x32x16_bf16(va0, pb.v, o0, 0, 0, 0);
      o1  = __builtin_amdgcn_mfma_f32_32x32x16_bf16(va1, pb.v, o1, 0, 0, 0);
      o_l = __builtin_amdgcn_mfma_f32_32x32x16_bf16(ones.v, pb.v, o_l, 0, 0, 0);
    }
    __builtin_amdgcn_s_setprio(0);
    cfence();
    __builtin_amdgcn_s_barrier();   // all waves done reading Vs[buf u]
    cfence();
    if (u + 2 < NT) stageV(u + 2, u & 1);
  };

  // prologue: stage tiles 0,1 (order K0,V0,K1,V1 = ledger base)
  stageK(0, 0); stageV(0, 0); stageK(1, 1); stageV(1, 1);
  asm volatile("s_waitcnt vmcnt(6)" ::: "memory");   // K(0) done
  __builtin_amdgcn_s_barrier();
  cfence();
  f32x16 pa0, pa1, pb0, pb1;
  qkt(0, pa0, pa1);

  for (int t = 0; t < NT; t += 2) {
    body(t,     pa0, pa1, pb0, pb1);
    body(t + 1, pb0, pb1, pa0, pa1);
  }

  const float inv = 1.f / o_l[0];
  u16* Ob = O + (size_t)(b * N_ + q0 + q) * D_ + h * 64;
#pragma unroll
  for (int rh = 0; rh < 4; ++rh) {
    uint2 s0, s1;
    s0.x = pk2(o0[4 * rh + 0] * inv, o0[4 * rh + 1] * inv);
    s0.y = pk2(o0[4 * rh + 2] * inv, o0[4 * rh + 3] * inv);
    s1.x = pk2(o1[4 * rh + 0] * inv, o1[4 * rh + 1] * inv);
    s1.y = pk2(o1[4 * rh + 2] * inv, o1[4 * rh + 3] * inv);
    *(uint2*)(Ob + 8 * rh + 4 * hi)      = s0;
    *(uint2*)(Ob + 32 + 8 * rh + 4 * hi) = s1;
  }
}

extern "C" void kernel_launch(void* const* d_in, const int* in_sizes, int n_in,
                              void* d_out, int out_size, void* d_ws, size_t ws_size,
                              hipStream_t stream) {
  const float* x  = (const float*)d_in[0];
  const float* Wq = (const float*)d_in[1];
  const float* Wk = (const float*)d_in[2];
  const float* Wv = (const float*)d_in[3];
  const float* Wo = (const float*)d_in[4];
  const float* bo = (const float*)d_in[5];
  float* out = (float*)d_out;

  char* ws = (char*)d_ws;
  u16* xb   = (u16*)(ws);                   // 8 MiB: x bf16; reused as VtG
  u16* Wb   = (u16*)(ws + (8ull << 20));    // 8 MiB: weights bf16 [Wq;Wk;Wv;Wo]
  u16* QKV  = (u16*)(ws + (16ull << 20));   // 24 MiB: Q,K,V bf16
  u16* Ob   = (u16*)(ws + (40ull << 20));   // 8 MiB: attn out
  u16* VtG  = xb;                           // transposed V (xb dead after QKV GEMM)

  cast_all<<<dim3(4096), dim3(256), 0, stream>>>(x, Wq, Wk, Wv, Wo, xb, Wb);

  // merged QKV GEMM: 128x128 tiles, BK=64 -> 768 blocks, 16 K-iters
  gemm_bt<0><<<dim3(24, 32), dim3(256), 0, stream>>>(
      xb, Wb, QKV, (size_t)(4096 * 1024), (const float*)nullptr,
      4096, 3072, 1024);

  vtrans<<<dim3(64, 16), dim3(256), 0, stream>>>(QKV + 2 * 4096 * 1024, VtG);

  attn_fused<<<dim3(16, 32), dim3(256), 0, stream>>>(
      QKV, QKV + 4096 * 1024, VtG, Ob);

  // out-proj: 128x128 tiles, BK=64 -> 256 blocks
  gemm_bt<1><<<dim3(8, 32), dim3(256), 0, stream>>>(
      Ob, Wb + 3 * 1048576, out, (size_t)0, bo, 4096, 1024, 1024);
}

// Round 22
// 126.906 us; speedup vs baseline: 1.0466x; 1.0466x over previous
//
#include <hip/hip_runtime.h>
#include <hip/hip_bf16.h>
#include <stdint.h>

// MHA fwd: B=2, N=2048, D=1024, H=16, HD=64, scale=0.125
#define B_ 2
#define N_ 2048
#define D_ 1024
#define H_ 16
#define SCALE_L2E 0.18033688011112042f  // 0.125 * log2(e): softmax in base-2 domain

typedef unsigned short u16;
typedef unsigned int u32;
using f32x4  = __attribute__((ext_vector_type(4))) float;
using f32x16 = __attribute__((ext_vector_type(16))) float;
using bf16x8 = __attribute__((ext_vector_type(8))) short;
using i16x8  = __attribute__((ext_vector_type(8))) short;

__device__ __forceinline__ u16 f2b(float f) {
  unsigned u = __float_as_uint(f);
  return (u16)((u + 0x7FFFu + ((u >> 16) & 1u)) >> 16);
}
// HW packed f32->bf16 (RNE), inline asm (no builtin on gfx950)
__device__ __forceinline__ u32 pk2(float lo, float hi) {
  u32 r;
  asm("v_cvt_pk_bf16_f32 %0, %1, %2" : "=v"(r) : "v"(lo), "v"(hi));
  return r;
}
__device__ __forceinline__ float ex2(float x) {
  return __builtin_amdgcn_exp2f(x);   // bare v_exp_f32; args bounded here
}
__device__ __forceinline__ void async16(const u16* g, u16* l) {
  __builtin_amdgcn_global_load_lds(
      (const __attribute__((address_space(1))) void*)g,
      (__attribute__((address_space(3))) void*)l, 16, 0, 0);
}
// full compiler fence: IR-level (memory clobber) + machine-scheduler
__device__ __forceinline__ void cfence() {
  asm volatile("" ::: "memory");
  __builtin_amdgcn_sched_barrier(0);
}

// one launch: cast x (4M elems) + Wq,Wk,Wv,Wo (4x1M elems) to bf16
__global__ __launch_bounds__(256) void cast_all(
    const float* __restrict__ x, const float* __restrict__ w0,
    const float* __restrict__ w1, const float* __restrict__ w2,
    const float* __restrict__ w3, u16* __restrict__ xb, u16* __restrict__ Wb) {
  const int i = (blockIdx.x * 256 + threadIdx.x) * 8;
  const float* s;
  u16* d;
  if (i < 4194304) { s = x + i; d = xb + i; }
  else {
    const int j = i - 4194304;
    const int wsel = j >> 20;
    const float* w = wsel == 0 ? w0 : wsel == 1 ? w1 : wsel == 2 ? w2 : w3;
    s = w + (j & 1048575);
    d = Wb + j;
  }
  union { u32 u[4]; i16x8 v; } o;
#pragma unroll
  for (int j = 0; j < 4; ++j) o.u[j] = pk2(s[2 * j], s[2 * j + 1]);
  *(i16x8*)d = o.v;
}

// C = A * Bt^T. 128M x 64N tile, BK=64, 4 waves (2x2 of 64x32).
// 16 K-iterations (half the vmcnt(0)+barrier drains of BK=32), full 8-chunk
// XOR swizzle on the [row][64] LDS tiles (pre-swizzled global source +
// swizzled read) -> conflict-free ds_read_b128.
// F32OUT==0: merged QKV GEMM — Bt is [3072][1024] (Wq;Wk;Wv); zsel = tN>>10;
// zsel==0 scaled by SCALE_L2E. F32OUT==1: fp32 out + bias.
template <int F32OUT>
__global__ __launch_bounds__(256) void gemm_bt(
    const u16* __restrict__ A, const u16* __restrict__ Bt,
    void* __restrict__ C0, size_t sCz, const float* __restrict__ bias,
    int M, int Nn, int K) {
  __shared__ __align__(16) u16 As[128 * 64];  // 16 KB, chunk-swizzled
  __shared__ __align__(16) u16 Bs[64 * 64];   //  8 KB, chunk-swizzled
  const int tid = threadIdx.x;
  const int w = tid >> 6, l = tid & 63;
  const int wm = w >> 1, wn = w & 1;
  const int la = l & 15, lb = l >> 4;
  const int tM = blockIdx.y * 128, tN = blockIdx.x * 64;

  const int srow8 = l >> 3;                    // 0..7 within an 8-row stripe
  const int scol  = ((l & 7) ^ srow8) << 3;    // pre-swizzled source chunk
  const u16* gA = A + (size_t)(tM + w * 32 + srow8) * K + scol;
  const u16* gB = Bt + (size_t)(tN + w * 16 + srow8) * K + scol;
  u16* lA = As + w * 2048;
  u16* lB = Bs + w * 1024;

  f32x4 acc[4][2] = {};

  for (int k0 = 0; k0 < K; k0 += 64) {
#pragma unroll
    for (int c = 0; c < 4; ++c)
      async16(gA + (size_t)(c * 8) * K, lA + c * 512);
#pragma unroll
    for (int c = 0; c < 2; ++c)
      async16(gB + (size_t)(c * 8) * K, lB + c * 512);
    gA += 64; gB += 64;
    __syncthreads();   // drains vmcnt: tiles resident
    bf16x8 af[4][2], bfr[2][2];
#pragma unroll
    for (int i = 0; i < 4; ++i) {
      const int row = wm * 64 + i * 16 + la;
#pragma unroll
      for (int kk = 0; kk < 2; ++kk)
        af[i][kk] = *(const bf16x8*)(As + row * 64 + (((kk * 4 + lb) ^ (row & 7)) << 3));
    }
#pragma unroll
    for (int j = 0; j < 2; ++j) {
      const int row = wn * 32 + j * 16 + la;
#pragma unroll
      for (int kk = 0; kk < 2; ++kk)
        bfr[j][kk] = *(const bf16x8*)(Bs + row * 64 + (((kk * 4 + lb) ^ (row & 7)) << 3));
    }
#pragma unroll
    for (int kk = 0; kk < 2; ++kk)
#pragma unroll
      for (int i = 0; i < 4; ++i)
#pragma unroll
        for (int j = 0; j < 2; ++j)
          acc[i][j] = __builtin_amdgcn_mfma_f32_16x16x32_bf16(
              af[i][kk], bfr[j][kk], acc[i][j], 0, 0, 0);
    __syncthreads();   // before next stage overwrites
  }

  const int zsel = F32OUT ? 0 : (tN >> 10);
  const int tNl = F32OUT ? tN : (tN & 1023);
  const float osc = (!F32OUT && zsel == 0) ? SCALE_L2E : 1.0f;
  const int ld = F32OUT ? Nn : 1024;
#pragma unroll
  for (int i = 0; i < 4; ++i) {
    const int row = tM + wm * 64 + i * 16 + lb * 4;
#pragma unroll
    for (int j = 0; j < 2; ++j) {
      const int col = tNl + wn * 32 + j * 16 + la;
#pragma unroll
      for (int r = 0; r < 4; ++r) {
        const float v = acc[i][j][r];
        if (F32OUT) {
          ((float*)C0)[(size_t)(row + r) * ld + col] = v + bias[col];
        } else {
          (((u16*)C0) + (size_t)zsel * sCz)[(size_t)(row + r) * ld + col] = f2b(v * osc);
        }
      }
    }
  }
}

// V [B*N][D] (per-head cols) -> VtG [(b*16+h)*64 + d][N]
__global__ __launch_bounds__(256) void vtrans(const u16* __restrict__ V,
                                              u16* __restrict__ Vt) {
  __shared__ u16 T[64][72];
  const int tid = threadIdx.x;
  const int rt = blockIdx.x, h = blockIdx.y;
  const int r = tid >> 3, c = (tid & 7) * 8;
#pragma unroll
  for (int p = 0; p < 2; ++p) {
    i16x8 v = *(const i16x8*)(V + (size_t)(rt * 64 + p * 32 + r) * D_ + h * 64 + c);
#pragma unroll
    for (int j = 0; j < 8; ++j) T[p * 32 + r][c + j] = (u16)v[j];
  }
  __syncthreads();
  const int b = rt >> 5, nb = (rt & 31) * 64;
#pragma unroll
  for (int p = 0; p < 2; ++p) {
    const int d = p * 32 + r;
    i16x8 o;
#pragma unroll
    for (int j = 0; j < 8; ++j) o[j] = (short)T[c + j][d];
    *(i16x8*)(Vt + ((size_t)((b * 16 + h) * 64 + d)) * (size_t)N_ + nb + c) = o;
  }
}

// Flash attention (R17 form — measured best): NSPLIT=1, swapped-QK^T 32x32,
// static softmax, key-permuted K staging, ones-MFMA row-sum, XCD remap,
// 2-buffer/vmcnt(4) pipeline with cfence'd raw barriers.
__global__ __launch_bounds__(256) void attn_fused(
    const u16* __restrict__ Q, const u16* __restrict__ Kb,
    const u16* __restrict__ VtG, u16* __restrict__ O) {
  __shared__ __align__(16) u16 Ks[2 * 64 * 64];
  __shared__ __align__(16) u16 Vs[2 * 64 * 64];
  const int tid = threadIdx.x;
  const int w = tid >> 6, l = tid & 63;
  const int q = l & 31, hi = l >> 5;

  const int flat = blockIdx.x + 16 * blockIdx.y;
  const int logical = (flat & 7) * 64 + (flat >> 3);
  const int qx = logical & 15;
  const int y  = logical >> 4;

  const int b = y >> 4, h = y & 15;
  const int q0 = qx * 128 + w * 32;

  const u16* Qrow = Q + (size_t)(b * N_ + q0 + q) * D_ + h * 64;
  bf16x8 qf[4];
#pragma unroll
  for (int s = 0; s < 4; ++s) qf[s] = *(const bf16x8*)(Qrow + s * 16 + hi * 8);

  const int srow = l >> 3;
  const int scol = ((l & 7) ^ srow) << 3;
  const int kprow = w * 16 + (srow & 3) + ((srow & 4) << 1);
  const u16* Kg = Kb + (size_t)(b * N_ + kprow) * D_ + h * 64 + scol;
  const u16* Vg = VtG + (size_t)(y * 64 + w * 16 + srow) * N_ + scol;

  const int qsw = (q & 7) << 3;
  const int qr0 = q * 64, qr1 = (32 + q) * 64;

  union { u32 u[4]; bf16x8 v; } ones;
#pragma unroll
  for (int j = 0; j < 4; ++j) ones.u[j] = 0x3F803F80u;

  f32x16 o0 = {}, o1 = {}, o_l = {};

  auto stage = [&](int t, int buf) {
    const u16* kg = Kg + (size_t)(t * 64) * D_;
    u16* kd = Ks + buf * 4096 + w * 1024;
    async16(kg, kd);
    async16(kg + (size_t)4 * D_, kd + 512);
    const u16* vg = Vg + t * 64;
    u16* vd = Vs + buf * 4096 + w * 1024;
    async16(vg, vd);
    async16(vg + (size_t)8 * N_, vd + 512);
  };

  const int NT = N_ / 64;  // 32
  stage(0, 0);
  stage(1, 1);

  for (int t = 0; t < NT; ++t) {
    const int buf = t & 1;
    if (t + 1 < NT) asm volatile("s_waitcnt vmcnt(4)" ::: "memory");
    else            asm volatile("s_waitcnt vmcnt(0)" ::: "memory");
    __builtin_amdgcn_s_barrier();
    cfence();
    const u16* KT = Ks + buf * 4096;
    const u16* VT = Vs + buf * 4096;

    f32x16 p0 = {}, p1 = {};
    __builtin_amdgcn_s_setprio(1);
#pragma unroll
    for (int s = 0; s < 4; ++s) {
      const int off = (s * 16 + hi * 8) ^ qsw;
      bf16x8 kf0 = *(const bf16x8*)(KT + qr0 + off);
      bf16x8 kf1 = *(const bf16x8*)(KT + qr1 + off);
      p0 = __builtin_amdgcn_mfma_f32_32x32x16_bf16(kf0, qf[s], p0, 0, 0, 0);
      p1 = __builtin_amdgcn_mfma_f32_32x32x16_bf16(kf1, qf[s], p1, 0, 0, 0);
    }
    __builtin_amdgcn_s_setprio(0);

#pragma unroll
    for (int r = 0; r < 16; ++r) p0[r] = ex2(p0[r]);
#pragma unroll
    for (int r = 0; r < 16; ++r) p1[r] = ex2(p1[r]);

    __builtin_amdgcn_s_setprio(1);
#pragma unroll
    for (int ks = 0; ks < 4; ++ks) {
      const f32x16& P = (ks < 2) ? p0 : p1;
      const int rbq = (ks & 1) * 8;
      union { u32 u[4]; bf16x8 v; } pb;
#pragma unroll
      for (int j = 0; j < 4; ++j) pb.u[j] = pk2(P[rbq + 2 * j], P[rbq + 2 * j + 1]);
      const int off = (ks * 16 + hi * 8) ^ qsw;
      bf16x8 va0 = *(const bf16x8*)(VT + qr0 + off);
      bf16x8 va1 = *(const bf16x8*)(VT + qr1 + off);
      o0  = __builtin_amdgcn_mfma_f32_32x32x16_bf16(va0, pb.v, o0, 0, 0, 0);
      o1  = __builtin_amdgcn_mfma_f32_32x32x16_bf16(va1, pb.v, o1, 0, 0, 0);
      o_l = __builtin_amdgcn_mfma_f32_32x32x16_bf16(ones.v, pb.v, o_l, 0, 0, 0);
    }
    __builtin_amdgcn_s_setprio(0);
    cfence();
    __builtin_amdgcn_s_barrier();
    cfence();
    if (t + 2 < NT) stage(t + 2, buf);
  }

  const float inv = 1.f / o_l[0];
  u16* Ob = O + (size_t)(b * N_ + q0 + q) * D_ + h * 64;
#pragma unroll
  for (int rh = 0; rh < 4; ++rh) {
    uint2 s0, s1;
    s0.x = pk2(o0[4 * rh + 0] * inv, o0[4 * rh + 1] * inv);
    s0.y = pk2(o0[4 * rh + 2] * inv, o0[4 * rh + 3] * inv);
    s1.x = pk2(o1[4 * rh + 0] * inv, o1[4 * rh + 1] * inv);
    s1.y = pk2(o1[4 * rh + 2] * inv, o1[4 * rh + 3] * inv);
    *(uint2*)(Ob + 8 * rh + 4 * hi)      = s0;
    *(uint2*)(Ob + 32 + 8 * rh + 4 * hi) = s1;
  }
}

extern "C" void kernel_launch(void* const* d_in, const int* in_sizes, int n_in,
                              void* d_out, int out_size, void* d_ws, size_t ws_size,
                              hipStream_t stream) {
  const float* x  = (const float*)d_in[0];
  const float* Wq = (const float*)d_in[1];
  const float* Wk = (const float*)d_in[2];
  const float* Wv = (const float*)d_in[3];
  const float* Wo = (const float*)d_in[4];
  const float* bo = (const float*)d_in[5];
  float* out = (float*)d_out;

  char* ws = (char*)d_ws;
  u16* xb   = (u16*)(ws);                   // 8 MiB: x bf16; reused as VtG
  u16* Wb   = (u16*)(ws + (8ull << 20));    // 8 MiB: weights bf16 [Wq;Wk;Wv;Wo]
  u16* QKV  = (u16*)(ws + (16ull << 20));   // 24 MiB: Q,K,V bf16
  u16* Ob   = (u16*)(ws + (40ull << 20));   // 8 MiB: attn out
  u16* VtG  = xb;                           // transposed V (xb dead after QKV GEMM)

  cast_all<<<dim3(4096), dim3(256), 0, stream>>>(x, Wq, Wk, Wv, Wo, xb, Wb);

  // merged QKV GEMM: 128x64 tiles, BK=64 -> 1536 blocks, 16 K-iters
  gemm_bt<0><<<dim3(48, 32), dim3(256), 0, stream>>>(
      xb, Wb, QKV, (size_t)(4096 * 1024), (const float*)nullptr,
      4096, 3072, 1024);

  vtrans<<<dim3(64, 16), dim3(256), 0, stream>>>(QKV + 2 * 4096 * 1024, VtG);

  attn_fused<<<dim3(16, 32), dim3(256), 0, stream>>>(
      QKV, QKV + 4096 * 1024, VtG, Ob);

  // out-proj: 128x64 tiles, BK=64 -> 512 blocks
  gemm_bt<1><<<dim3(16, 32), dim3(256), 0, stream>>>(
      Ob, Wb + 3 * 1048576, out, (size_t)0, bo, 4096, 1024, 1024);
}

// Round 23
// 118.019 us; speedup vs baseline: 1.1255x; 1.0753x over previous
//
#include <hip/hip_runtime.h>
#include <hip/hip_bf16.h>
#include <stdint.h>

// MHA fwd: B=2, N=2048, D=1024, H=16, HD=64, scale=0.125
#define B_ 2
#define N_ 2048
#define D_ 1024
#define H_ 16
#define SCALE_L2E 0.18033688011112042f  // 0.125 * log2(e): softmax in base-2 domain

typedef unsigned short u16;
typedef unsigned int u32;
using f32x4  = __attribute__((ext_vector_type(4))) float;
using f32x16 = __attribute__((ext_vector_type(16))) float;
using bf16x8 = __attribute__((ext_vector_type(8))) short;
using i16x8  = __attribute__((ext_vector_type(8))) short;

__device__ __forceinline__ u16 f2b(float f) {
  unsigned u = __float_as_uint(f);
  return (u16)((u + 0x7FFFu + ((u >> 16) & 1u)) >> 16);
}
// HW packed f32->bf16 (RNE), inline asm (no builtin on gfx950)
__device__ __forceinline__ u32 pk2(float lo, float hi) {
  u32 r;
  asm("v_cvt_pk_bf16_f32 %0, %1, %2" : "=v"(r) : "v"(lo), "v"(hi));
  return r;
}
__device__ __forceinline__ float ex2(float x) {
  return __builtin_amdgcn_exp2f(x);   // bare v_exp_f32; args bounded here
}
__device__ __forceinline__ void async16(const u16* g, u16* l) {
  __builtin_amdgcn_global_load_lds(
      (const __attribute__((address_space(1))) void*)g,
      (__attribute__((address_space(3))) void*)l, 16, 0, 0);
}
// full compiler fence: IR-level (memory clobber) + machine-scheduler
__device__ __forceinline__ void cfence() {
  asm volatile("" ::: "memory");
  __builtin_amdgcn_sched_barrier(0);
}

// one launch: cast x (4M elems) + Wq,Wk,Wv,Wo (4x1M elems) to bf16
__global__ __launch_bounds__(256) void cast_all(
    const float* __restrict__ x, const float* __restrict__ w0,
    const float* __restrict__ w1, const float* __restrict__ w2,
    const float* __restrict__ w3, u16* __restrict__ xb, u16* __restrict__ Wb) {
  const int i = (blockIdx.x * 256 + threadIdx.x) * 8;
  const float* s;
  u16* d;
  if (i < 4194304) { s = x + i; d = xb + i; }
  else {
    const int j = i - 4194304;
    const int wsel = j >> 20;
    const float* w = wsel == 0 ? w0 : wsel == 1 ? w1 : wsel == 2 ? w2 : w3;
    s = w + (j & 1048575);
    d = Wb + j;
  }
  union { u32 u[4]; i16x8 v; } o;
#pragma unroll
  for (int j = 0; j < 4; ++j) o.u[j] = pk2(s[2 * j], s[2 * j + 1]);
  *(i16x8*)d = o.v;
}

// C = A * Bt^T. 128M x 64N tile, BK=64, 4 waves (2x2 of 64x32).
// NEW: counted-vmcnt 2-deep DOUBLE-BUFFER pipeline (attn's proven skeleton):
// per iter wait vmcnt(6) — drains exactly tile t's 6 loads (issued TWO
// iterations ago, latency fully hidden); tile t+1's 6 stay in flight across
// both barriers. Replaces __syncthreads' vmcnt(0) drain of fresh loads.
// cfence on all raw-barrier edges (s_barrier builtin is IntrNoMem).
// Both-sides chunk-XOR swizzle -> conflict-free ds_read_b128.
// F32OUT==0: merged QKV GEMM — Bt is [3072][1024] (Wq;Wk;Wv); zsel = tN>>10;
// zsel==0 scaled by SCALE_L2E. F32OUT==1: fp32 out + bias.
template <int F32OUT>
__global__ __launch_bounds__(256) void gemm_bt(
    const u16* __restrict__ A, const u16* __restrict__ Bt,
    void* __restrict__ C0, size_t sCz, const float* __restrict__ bias,
    int M, int Nn, int K) {
  __shared__ __align__(16) u16 As[2][128 * 64];  // 32 KB, chunk-swizzled
  __shared__ __align__(16) u16 Bs[2][64 * 64];   // 16 KB, chunk-swizzled
  const int tid = threadIdx.x;
  const int w = tid >> 6, l = tid & 63;
  const int wm = w >> 1, wn = w & 1;
  const int la = l & 15, lb = l >> 4;
  const int tM = blockIdx.y * 128, tN = blockIdx.x * 64;

  const int srow8 = l >> 3;                    // 0..7 within an 8-row stripe
  const int scol  = ((l & 7) ^ srow8) << 3;    // pre-swizzled source chunk
  const u16* gA = A + (size_t)(tM + w * 32 + srow8) * K + scol;
  const u16* gB = Bt + (size_t)(tN + w * 16 + srow8) * K + scol;

  // exactly 6 VMEM ops per wave per stage (vmcnt ledger depends on this)
  auto stage = [&](int t, int buf) {
    const int ko = t * 64;
    u16* lA = As[buf] + w * 2048;
    u16* lB = Bs[buf] + w * 1024;
#pragma unroll
    for (int c = 0; c < 4; ++c)
      async16(gA + (size_t)(c * 8) * K + ko, lA + c * 512);
#pragma unroll
    for (int c = 0; c < 2; ++c)
      async16(gB + (size_t)(c * 8) * K + ko, lB + c * 512);
  };

  f32x4 acc[4][2] = {};
  const int NT = K / 64;  // 16
  stage(0, 0);
  stage(1, 1);

  for (int t = 0; t < NT; ++t) {
    const int buf = t & 1;
    // counted wait: oldest 6 outstanding = tile t's loads (issued 2 iters ago)
    if (t + 1 < NT) asm volatile("s_waitcnt vmcnt(6)" ::: "memory");
    else            asm volatile("s_waitcnt vmcnt(0)" ::: "memory");
    __builtin_amdgcn_s_barrier();   // tile t resident for all waves
    cfence();                       // no ds_read may float above the barrier
    bf16x8 af[4][2], bfr[2][2];
#pragma unroll
    for (int i = 0; i < 4; ++i) {
      const int row = wm * 64 + i * 16 + la;
#pragma unroll
      for (int kk = 0; kk < 2; ++kk)
        af[i][kk] = *(const bf16x8*)(As[buf] + row * 64 + (((kk * 4 + lb) ^ (row & 7)) << 3));
    }
#pragma unroll
    for (int j = 0; j < 2; ++j) {
      const int row = wn * 32 + j * 16 + la;
#pragma unroll
      for (int kk = 0; kk < 2; ++kk)
        bfr[j][kk] = *(const bf16x8*)(Bs[buf] + row * 64 + (((kk * 4 + lb) ^ (row & 7)) << 3));
    }
#pragma unroll
    for (int kk = 0; kk < 2; ++kk)
#pragma unroll
      for (int i = 0; i < 4; ++i)
#pragma unroll
        for (int j = 0; j < 2; ++j)
          acc[i][j] = __builtin_amdgcn_mfma_f32_16x16x32_bf16(
              af[i][kk], bfr[j][kk], acc[i][j], 0, 0, 0);
    cfence();                       // reads of buf pinned above the barrier
    __builtin_amdgcn_s_barrier();   // all waves done reading buf
    cfence();                       // DMA issue may not float above the barrier
    if (t + 2 < NT) stage(t + 2, buf);  // refill freed buffer; stays in flight
  }

  const int zsel = F32OUT ? 0 : (tN >> 10);
  const int tNl = F32OUT ? tN : (tN & 1023);
  const float osc = (!F32OUT && zsel == 0) ? SCALE_L2E : 1.0f;
  const int ld = F32OUT ? Nn : 1024;
#pragma unroll
  for (int i = 0; i < 4; ++i) {
    const int row = tM + wm * 64 + i * 16 + lb * 4;
#pragma unroll
    for (int j = 0; j < 2; ++j) {
      const int col = tNl + wn * 32 + j * 16 + la;
#pragma unroll
      for (int r = 0; r < 4; ++r) {
        const float v = acc[i][j][r];
        if (F32OUT) {
          ((float*)C0)[(size_t)(row + r) * ld + col] = v + bias[col];
        } else {
          (((u16*)C0) + (size_t)zsel * sCz)[(size_t)(row + r) * ld + col] = f2b(v * osc);
        }
      }
    }
  }
}

// V [B*N][D] (per-head cols) -> VtG [(b*16+h)*64 + d][N]
__global__ __launch_bounds__(256) void vtrans(const u16* __restrict__ V,
                                              u16* __restrict__ Vt) {
  __shared__ u16 T[64][72];
  const int tid = threadIdx.x;
  const int rt = blockIdx.x, h = blockIdx.y;
  const int r = tid >> 3, c = (tid & 7) * 8;
#pragma unroll
  for (int p = 0; p < 2; ++p) {
    i16x8 v = *(const i16x8*)(V + (size_t)(rt * 64 + p * 32 + r) * D_ + h * 64 + c);
#pragma unroll
    for (int j = 0; j < 8; ++j) T[p * 32 + r][c + j] = (u16)v[j];
  }
  __syncthreads();
  const int b = rt >> 5, nb = (rt & 31) * 64;
#pragma unroll
  for (int p = 0; p < 2; ++p) {
    const int d = p * 32 + r;
    i16x8 o;
#pragma unroll
    for (int j = 0; j < 8; ++j) o[j] = (short)T[c + j][d];
    *(i16x8*)(Vt + ((size_t)((b * 16 + h) * 64 + d)) * (size_t)N_ + nb + c) = o;
  }
}

// Flash attention (R17 form — measured best): NSPLIT=1, swapped-QK^T 32x32,
// static softmax, key-permuted K staging, ones-MFMA row-sum, XCD remap,
// 2-buffer/vmcnt(4) pipeline with cfence'd raw barriers.
__global__ __launch_bounds__(256) void attn_fused(
    const u16* __restrict__ Q, const u16* __restrict__ Kb,
    const u16* __restrict__ VtG, u16* __restrict__ O) {
  __shared__ __align__(16) u16 Ks[2 * 64 * 64];
  __shared__ __align__(16) u16 Vs[2 * 64 * 64];
  const int tid = threadIdx.x;
  const int w = tid >> 6, l = tid & 63;
  const int q = l & 31, hi = l >> 5;

  const int flat = blockIdx.x + 16 * blockIdx.y;
  const int logical = (flat & 7) * 64 + (flat >> 3);
  const int qx = logical & 15;
  const int y  = logical >> 4;

  const int b = y >> 4, h = y & 15;
  const int q0 = qx * 128 + w * 32;

  const u16* Qrow = Q + (size_t)(b * N_ + q0 + q) * D_ + h * 64;
  bf16x8 qf[4];
#pragma unroll
  for (int s = 0; s < 4; ++s) qf[s] = *(const bf16x8*)(Qrow + s * 16 + hi * 8);

  const int srow = l >> 3;
  const int scol = ((l & 7) ^ srow) << 3;
  const int kprow = w * 16 + (srow & 3) + ((srow & 4) << 1);
  const u16* Kg = Kb + (size_t)(b * N_ + kprow) * D_ + h * 64 + scol;
  const u16* Vg = VtG + (size_t)(y * 64 + w * 16 + srow) * N_ + scol;

  const int qsw = (q & 7) << 3;
  const int qr0 = q * 64, qr1 = (32 + q) * 64;

  union { u32 u[4]; bf16x8 v; } ones;
#pragma unroll
  for (int j = 0; j < 4; ++j) ones.u[j] = 0x3F803F80u;

  f32x16 o0 = {}, o1 = {}, o_l = {};

  auto stage = [&](int t, int buf) {
    const u16* kg = Kg + (size_t)(t * 64) * D_;
    u16* kd = Ks + buf * 4096 + w * 1024;
    async16(kg, kd);
    async16(kg + (size_t)4 * D_, kd + 512);
    const u16* vg = Vg + t * 64;
    u16* vd = Vs + buf * 4096 + w * 1024;
    async16(vg, vd);
    async16(vg + (size_t)8 * N_, vd + 512);
  };

  const int NT = N_ / 64;  // 32
  stage(0, 0);
  stage(1, 1);

  for (int t = 0; t < NT; ++t) {
    const int buf = t & 1;
    if (t + 1 < NT) asm volatile("s_waitcnt vmcnt(4)" ::: "memory");
    else            asm volatile("s_waitcnt vmcnt(0)" ::: "memory");
    __builtin_amdgcn_s_barrier();
    cfence();
    const u16* KT = Ks + buf * 4096;
    const u16* VT = Vs + buf * 4096;

    f32x16 p0 = {}, p1 = {};
    __builtin_amdgcn_s_setprio(1);
#pragma unroll
    for (int s = 0; s < 4; ++s) {
      const int off = (s * 16 + hi * 8) ^ qsw;
      bf16x8 kf0 = *(const bf16x8*)(KT + qr0 + off);
      bf16x8 kf1 = *(const bf16x8*)(KT + qr1 + off);
      p0 = __builtin_amdgcn_mfma_f32_32x32x16_bf16(kf0, qf[s], p0, 0, 0, 0);
      p1 = __builtin_amdgcn_mfma_f32_32x32x16_bf16(kf1, qf[s], p1, 0, 0, 0);
    }
    __builtin_amdgcn_s_setprio(0);

#pragma unroll
    for (int r = 0; r < 16; ++r) p0[r] = ex2(p0[r]);
#pragma unroll
    for (int r = 0; r < 16; ++r) p1[r] = ex2(p1[r]);

    __builtin_amdgcn_s_setprio(1);
#pragma unroll
    for (int ks = 0; ks < 4; ++ks) {
      const f32x16& P = (ks < 2) ? p0 : p1;
      const int rbq = (ks & 1) * 8;
      union { u32 u[4]; bf16x8 v; } pb;
#pragma unroll
      for (int j = 0; j < 4; ++j) pb.u[j] = pk2(P[rbq + 2 * j], P[rbq + 2 * j + 1]);
      const int off = (ks * 16 + hi * 8) ^ qsw;
      bf16x8 va0 = *(const bf16x8*)(VT + qr0 + off);
      bf16x8 va1 = *(const bf16x8*)(VT + qr1 + off);
      o0  = __builtin_amdgcn_mfma_f32_32x32x16_bf16(va0, pb.v, o0, 0, 0, 0);
      o1  = __builtin_amdgcn_mfma_f32_32x32x16_bf16(va1, pb.v, o1, 0, 0, 0);
      o_l = __builtin_amdgcn_mfma_f32_32x32x16_bf16(ones.v, pb.v, o_l, 0, 0, 0);
    }
    __builtin_amdgcn_s_setprio(0);
    cfence();
    __builtin_amdgcn_s_barrier();
    cfence();
    if (t + 2 < NT) stage(t + 2, buf);
  }

  const float inv = 1.f / o_l[0];
  u16* Ob = O + (size_t)(b * N_ + q0 + q) * D_ + h * 64;
#pragma unroll
  for (int rh = 0; rh < 4; ++rh) {
    uint2 s0, s1;
    s0.x = pk2(o0[4 * rh + 0] * inv, o0[4 * rh + 1] * inv);
    s0.y = pk2(o0[4 * rh + 2] * inv, o0[4 * rh + 3] * inv);
    s1.x = pk2(o1[4 * rh + 0] * inv, o1[4 * rh + 1] * inv);
    s1.y = pk2(o1[4 * rh + 2] * inv, o1[4 * rh + 3] * inv);
    *(uint2*)(Ob + 8 * rh + 4 * hi)      = s0;
    *(uint2*)(Ob + 32 + 8 * rh + 4 * hi) = s1;
  }
}

extern "C" void kernel_launch(void* const* d_in, const int* in_sizes, int n_in,
                              void* d_out, int out_size, void* d_ws, size_t ws_size,
                              hipStream_t stream) {
  const float* x  = (const float*)d_in[0];
  const float* Wq = (const float*)d_in[1];
  const float* Wk = (const float*)d_in[2];
  const float* Wv = (const float*)d_in[3];
  const float* Wo = (const float*)d_in[4];
  const float* bo = (const float*)d_in[5];
  float* out = (float*)d_out;

  char* ws = (char*)d_ws;
  u16* xb   = (u16*)(ws);                   // 8 MiB: x bf16; reused as VtG
  u16* Wb   = (u16*)(ws + (8ull << 20));    // 8 MiB: weights bf16 [Wq;Wk;Wv;Wo]
  u16* QKV  = (u16*)(ws + (16ull << 20));   // 24 MiB: Q,K,V bf16
  u16* Ob   = (u16*)(ws + (40ull << 20));   // 8 MiB: attn out
  u16* VtG  = xb;                           // transposed V (xb dead after QKV GEMM)

  cast_all<<<dim3(4096), dim3(256), 0, stream>>>(x, Wq, Wk, Wv, Wo, xb, Wb);

  // merged QKV GEMM: 128x64 tiles, BK=64, counted-vmcnt dbuf pipeline
  gemm_bt<0><<<dim3(48, 32), dim3(256), 0, stream>>>(
      xb, Wb, QKV, (size_t)(4096 * 1024), (const float*)nullptr,
      4096, 3072, 1024);

  vtrans<<<dim3(64, 16), dim3(256), 0, stream>>>(QKV + 2 * 4096 * 1024, VtG);

  attn_fused<<<dim3(16, 32), dim3(256), 0, stream>>>(
      QKV, QKV + 4096 * 1024, VtG, Ob);

  // out-proj: 128x64 tiles, BK=64, counted-vmcnt dbuf pipeline
  gemm_bt<1><<<dim3(16, 32), dim3(256), 0, stream>>>(
      Ob, Wb + 3 * 1048576, out, (size_t)0, bo, 4096, 1024, 1024);
}

// Round 24
// 117.485 us; speedup vs baseline: 1.1306x; 1.0045x over previous
//
#include <hip/hip_runtime.h>
#include <hip/hip_bf16.h>
#include <stdint.h>

// MHA fwd: B=2, N=2048, D=1024, H=16, HD=64, scale=0.125
#define B_ 2
#define N_ 2048
#define D_ 1024
#define H_ 16
#define SCALE_L2E 0.18033688011112042f  // 0.125 * log2(e): softmax in base-2 domain

typedef unsigned short u16;
typedef unsigned int u32;
using f32x4  = __attribute__((ext_vector_type(4))) float;
using f32x16 = __attribute__((ext_vector_type(16))) float;
using bf16x8 = __attribute__((ext_vector_type(8))) short;
using i16x8  = __attribute__((ext_vector_type(8))) short;

__device__ __forceinline__ u16 f2b(float f) {
  unsigned u = __float_as_uint(f);
  return (u16)((u + 0x7FFFu + ((u >> 16) & 1u)) >> 16);
}
// HW packed f32->bf16 (RNE), inline asm (no builtin on gfx950)
__device__ __forceinline__ u32 pk2(float lo, float hi) {
  u32 r;
  asm("v_cvt_pk_bf16_f32 %0, %1, %2" : "=v"(r) : "v"(lo), "v"(hi));
  return r;
}
__device__ __forceinline__ float ex2(float x) {
  return __builtin_amdgcn_exp2f(x);   // bare v_exp_f32; args bounded here
}
__device__ __forceinline__ void async16(const u16* g, u16* l) {
  __builtin_amdgcn_global_load_lds(
      (const __attribute__((address_space(1))) void*)g,
      (__attribute__((address_space(3))) void*)l, 16, 0, 0);
}
// full compiler fence: IR-level (memory clobber) + machine-scheduler
__device__ __forceinline__ void cfence() {
  asm volatile("" ::: "memory");
  __builtin_amdgcn_sched_barrier(0);
}

// one launch: cast x (4M elems) + Wq,Wk,Wv,Wo (4x1M elems) to bf16.
// G13: float4-vectorized source reads (2x dwordx4/thread, 16B/lane).
__global__ __launch_bounds__(256) void cast_all(
    const float* __restrict__ x, const float* __restrict__ w0,
    const float* __restrict__ w1, const float* __restrict__ w2,
    const float* __restrict__ w3, u16* __restrict__ xb, u16* __restrict__ Wb) {
  const int i = (blockIdx.x * 256 + threadIdx.x) * 8;
  const float* s;
  u16* d;
  if (i < 4194304) { s = x + i; d = xb + i; }
  else {
    const int j = i - 4194304;
    const int wsel = j >> 20;
    const float* w = wsel == 0 ? w0 : wsel == 1 ? w1 : wsel == 2 ? w2 : w3;
    s = w + (j & 1048575);
    d = Wb + j;
  }
  const f32x4 a = *(const f32x4*)(s);
  const f32x4 b = *(const f32x4*)(s + 4);
  union { u32 u[4]; i16x8 v; } o;
  o.u[0] = pk2(a[0], a[1]);
  o.u[1] = pk2(a[2], a[3]);
  o.u[2] = pk2(b[0], b[1]);
  o.u[3] = pk2(b[2], b[3]);
  *(i16x8*)d = o.v;
}

// C = A * Bt^T. 128M x 64N tile, BK=64, 4 waves (2x2 of 64x32).
// Counted-vmcnt 2-deep double-buffer pipeline: per iter wait vmcnt(6) —
// drains exactly tile t's 6 loads (issued TWO iterations ago, latency fully
// hidden); tile t+1's 6 stay in flight across both barriers. cfence on all
// raw-barrier edges (s_barrier builtin is IntrNoMem). Both-sides chunk-XOR
// swizzle -> conflict-free ds_read_b128.
// F32OUT==0: merged QKV GEMM — Bt is [3072][1024] (Wq;Wk;Wv); zsel = tN>>10;
// zsel==0 scaled by SCALE_L2E. F32OUT==1: fp32 out + bias.
template <int F32OUT>
__global__ __launch_bounds__(256) void gemm_bt(
    const u16* __restrict__ A, const u16* __restrict__ Bt,
    void* __restrict__ C0, size_t sCz, const float* __restrict__ bias,
    int M, int Nn, int K) {
  __shared__ __align__(16) u16 As[2][128 * 64];  // 32 KB, chunk-swizzled
  __shared__ __align__(16) u16 Bs[2][64 * 64];   // 16 KB, chunk-swizzled
  const int tid = threadIdx.x;
  const int w = tid >> 6, l = tid & 63;
  const int wm = w >> 1, wn = w & 1;
  const int la = l & 15, lb = l >> 4;
  const int tM = blockIdx.y * 128, tN = blockIdx.x * 64;

  const int srow8 = l >> 3;                    // 0..7 within an 8-row stripe
  const int scol  = ((l & 7) ^ srow8) << 3;    // pre-swizzled source chunk
  const u16* gA = A + (size_t)(tM + w * 32 + srow8) * K + scol;
  const u16* gB = Bt + (size_t)(tN + w * 16 + srow8) * K + scol;

  // exactly 6 VMEM ops per wave per stage (vmcnt ledger depends on this)
  auto stage = [&](int t, int buf) {
    const int ko = t * 64;
    u16* lA = As[buf] + w * 2048;
    u16* lB = Bs[buf] + w * 1024;
#pragma unroll
    for (int c = 0; c < 4; ++c)
      async16(gA + (size_t)(c * 8) * K + ko, lA + c * 512);
#pragma unroll
    for (int c = 0; c < 2; ++c)
      async16(gB + (size_t)(c * 8) * K + ko, lB + c * 512);
  };

  f32x4 acc[4][2] = {};
  const int NT = K / 64;  // 16
  stage(0, 0);
  stage(1, 1);

  for (int t = 0; t < NT; ++t) {
    const int buf = t & 1;
    // counted wait: oldest 6 outstanding = tile t's loads (issued 2 iters ago)
    if (t + 1 < NT) asm volatile("s_waitcnt vmcnt(6)" ::: "memory");
    else            asm volatile("s_waitcnt vmcnt(0)" ::: "memory");
    __builtin_amdgcn_s_barrier();   // tile t resident for all waves
    cfence();                       // no ds_read may float above the barrier
    bf16x8 af[4][2], bfr[2][2];
#pragma unroll
    for (int i = 0; i < 4; ++i) {
      const int row = wm * 64 + i * 16 + la;
#pragma unroll
      for (int kk = 0; kk < 2; ++kk)
        af[i][kk] = *(const bf16x8*)(As[buf] + row * 64 + (((kk * 4 + lb) ^ (row & 7)) << 3));
    }
#pragma unroll
    for (int j = 0; j < 2; ++j) {
      const int row = wn * 32 + j * 16 + la;
#pragma unroll
      for (int kk = 0; kk < 2; ++kk)
        bfr[j][kk] = *(const bf16x8*)(Bs[buf] + row * 64 + (((kk * 4 + lb) ^ (row & 7)) << 3));
    }
#pragma unroll
    for (int kk = 0; kk < 2; ++kk)
#pragma unroll
      for (int i = 0; i < 4; ++i)
#pragma unroll
        for (int j = 0; j < 2; ++j)
          acc[i][j] = __builtin_amdgcn_mfma_f32_16x16x32_bf16(
              af[i][kk], bfr[j][kk], acc[i][j], 0, 0, 0);
    cfence();                       // reads of buf pinned above the barrier
    __builtin_amdgcn_s_barrier();   // all waves done reading buf
    cfence();                       // DMA issue may not float above the barrier
    if (t + 2 < NT) stage(t + 2, buf);  // refill freed buffer; stays in flight
  }

  const int zsel = F32OUT ? 0 : (tN >> 10);
  const int tNl = F32OUT ? tN : (tN & 1023);
  const float osc = (!F32OUT && zsel == 0) ? SCALE_L2E : 1.0f;
  const int ld = F32OUT ? Nn : 1024;
#pragma unroll
  for (int i = 0; i < 4; ++i) {
    const int row = tM + wm * 64 + i * 16 + lb * 4;
#pragma unroll
    for (int j = 0; j < 2; ++j) {
      const int col = tNl + wn * 32 + j * 16 + la;
#pragma unroll
      for (int r = 0; r < 4; ++r) {
        const float v = acc[i][j][r];
        if (F32OUT) {
          ((float*)C0)[(size_t)(row + r) * ld + col] = v + bias[col];
        } else {
          (((u16*)C0) + (size_t)zsel * sCz)[(size_t)(row + r) * ld + col] = f2b(v * osc);
        }
      }
    }
  }
}

// V [B*N][D] (per-head cols) -> VtG [(b*16+h)*64 + d][N]
__global__ __launch_bounds__(256) void vtrans(const u16* __restrict__ V,
                                              u16* __restrict__ Vt) {
  __shared__ u16 T[64][72];
  const int tid = threadIdx.x;
  const int rt = blockIdx.x, h = blockIdx.y;
  const int r = tid >> 3, c = (tid & 7) * 8;
#pragma unroll
  for (int p = 0; p < 2; ++p) {
    i16x8 v = *(const i16x8*)(V + (size_t)(rt * 64 + p * 32 + r) * D_ + h * 64 + c);
#pragma unroll
    for (int j = 0; j < 8; ++j) T[p * 32 + r][c + j] = (u16)v[j];
  }
  __syncthreads();
  const int b = rt >> 5, nb = (rt & 31) * 64;
#pragma unroll
  for (int p = 0; p < 2; ++p) {
    const int d = p * 32 + r;
    i16x8 o;
#pragma unroll
    for (int j = 0; j < 8; ++j) o[j] = (short)T[c + j][d];
    *(i16x8*)(Vt + ((size_t)((b * 16 + h) * 64 + d)) * (size_t)N_ + nb + c) = o;
  }
}

// Flash attention (R17 form — measured best): NSPLIT=1, swapped-QK^T 32x32,
// static softmax, key-permuted K staging, ones-MFMA row-sum, XCD remap,
// 2-buffer/vmcnt(4) pipeline with cfence'd raw barriers.
__global__ __launch_bounds__(256) void attn_fused(
    const u16* __restrict__ Q, const u16* __restrict__ Kb,
    const u16* __restrict__ VtG, u16* __restrict__ O) {
  __shared__ __align__(16) u16 Ks[2 * 64 * 64];
  __shared__ __align__(16) u16 Vs[2 * 64 * 64];
  const int tid = threadIdx.x;
  const int w = tid >> 6, l = tid & 63;
  const int q = l & 31, hi = l >> 5;

  const int flat = blockIdx.x + 16 * blockIdx.y;
  const int logical = (flat & 7) * 64 + (flat >> 3);
  const int qx = logical & 15;
  const int y  = logical >> 4;

  const int b = y >> 4, h = y & 15;
  const int q0 = qx * 128 + w * 32;

  const u16* Qrow = Q + (size_t)(b * N_ + q0 + q) * D_ + h * 64;
  bf16x8 qf[4];
#pragma unroll
  for (int s = 0; s < 4; ++s) qf[s] = *(const bf16x8*)(Qrow + s * 16 + hi * 8);

  const int srow = l >> 3;
  const int scol = ((l & 7) ^ srow) << 3;
  const int kprow = w * 16 + (srow & 3) + ((srow & 4) << 1);
  const u16* Kg = Kb + (size_t)(b * N_ + kprow) * D_ + h * 64 + scol;
  const u16* Vg = VtG + (size_t)(y * 64 + w * 16 + srow) * N_ + scol;

  const int qsw = (q & 7) << 3;
  const int qr0 = q * 64, qr1 = (32 + q) * 64;

  union { u32 u[4]; bf16x8 v; } ones;
#pragma unroll
  for (int j = 0; j < 4; ++j) ones.u[j] = 0x3F803F80u;

  f32x16 o0 = {}, o1 = {}, o_l = {};

  auto stage = [&](int t, int buf) {
    const u16* kg = Kg + (size_t)(t * 64) * D_;
    u16* kd = Ks + buf * 4096 + w * 1024;
    async16(kg, kd);
    async16(kg + (size_t)4 * D_, kd + 512);
    const u16* vg = Vg + t * 64;
    u16* vd = Vs + buf * 4096 + w * 1024;
    async16(vg, vd);
    async16(vg + (size_t)8 * N_, vd + 512);
  };

  const int NT = N_ / 64;  // 32
  stage(0, 0);
  stage(1, 1);

  for (int t = 0; t < NT; ++t) {
    const int buf = t & 1;
    if (t + 1 < NT) asm volatile("s_waitcnt vmcnt(4)" ::: "memory");
    else            asm volatile("s_waitcnt vmcnt(0)" ::: "memory");
    __builtin_amdgcn_s_barrier();
    cfence();
    const u16* KT = Ks + buf * 4096;
    const u16* VT = Vs + buf * 4096;

    f32x16 p0 = {}, p1 = {};
    __builtin_amdgcn_s_setprio(1);
#pragma unroll
    for (int s = 0; s < 4; ++s) {
      const int off = (s * 16 + hi * 8) ^ qsw;
      bf16x8 kf0 = *(const bf16x8*)(KT + qr0 + off);
      bf16x8 kf1 = *(const bf16x8*)(KT + qr1 + off);
      p0 = __builtin_amdgcn_mfma_f32_32x32x16_bf16(kf0, qf[s], p0, 0, 0, 0);
      p1 = __builtin_amdgcn_mfma_f32_32x32x16_bf16(kf1, qf[s], p1, 0, 0, 0);
    }
    __builtin_amdgcn_s_setprio(0);

#pragma unroll
    for (int r = 0; r < 16; ++r) p0[r] = ex2(p0[r]);
#pragma unroll
    for (int r = 0; r < 16; ++r) p1[r] = ex2(p1[r]);

    __builtin_amdgcn_s_setprio(1);
#pragma unroll
    for (int ks = 0; ks < 4; ++ks) {
      const f32x16& P = (ks < 2) ? p0 : p1;
      const int rbq = (ks & 1) * 8;
      union { u32 u[4]; bf16x8 v; } pb;
#pragma unroll
      for (int j = 0; j < 4; ++j) pb.u[j] = pk2(P[rbq + 2 * j], P[rbq + 2 * j + 1]);
      const int off = (ks * 16 + hi * 8) ^ qsw;
      bf16x8 va0 = *(const bf16x8*)(VT + qr0 + off);
      bf16x8 va1 = *(const bf16x8*)(VT + qr1 + off);
      o0  = __builtin_amdgcn_mfma_f32_32x32x16_bf16(va0, pb.v, o0, 0, 0, 0);
      o1  = __builtin_amdgcn_mfma_f32_32x32x16_bf16(va1, pb.v, o1, 0, 0, 0);
      o_l = __builtin_amdgcn_mfma_f32_32x32x16_bf16(ones.v, pb.v, o_l, 0, 0, 0);
    }
    __builtin_amdgcn_s_setprio(0);
    cfence();
    __builtin_amdgcn_s_barrier();
    cfence();
    if (t + 2 < NT) stage(t + 2, buf);
  }

  const float inv = 1.f / o_l[0];
  u16* Ob = O + (size_t)(b * N_ + q0 + q) * D_ + h * 64;
#pragma unroll
  for (int rh = 0; rh < 4; ++rh) {
    uint2 s0, s1;
    s0.x = pk2(o0[4 * rh + 0] * inv, o0[4 * rh + 1] * inv);
    s0.y = pk2(o0[4 * rh + 2] * inv, o0[4 * rh + 3] * inv);
    s1.x = pk2(o1[4 * rh + 0] * inv, o1[4 * rh + 1] * inv);
    s1.y = pk2(o1[4 * rh + 2] * inv, o1[4 * rh + 3] * inv);
    *(uint2*)(Ob + 8 * rh + 4 * hi)      = s0;
    *(uint2*)(Ob + 32 + 8 * rh + 4 * hi) = s1;
  }
}

extern "C" void kernel_launch(void* const* d_in, const int* in_sizes, int n_in,
                              void* d_out, int out_size, void* d_ws, size_t ws_size,
                              hipStream_t stream) {
  const float* x  = (const float*)d_in[0];
  const float* Wq = (const float*)d_in[1];
  const float* Wk = (const float*)d_in[2];
  const float* Wv = (const float*)d_in[3];
  const float* Wo = (const float*)d_in[4];
  const float* bo = (const float*)d_in[5];
  float* out = (float*)d_out;

  char* ws = (char*)d_ws;
  u16* xb   = (u16*)(ws);                   // 8 MiB: x bf16; reused as VtG
  u16* Wb   = (u16*)(ws + (8ull << 20));    // 8 MiB: weights bf16 [Wq;Wk;Wv;Wo]
  u16* QKV  = (u16*)(ws + (16ull << 20));   // 24 MiB: Q,K,V bf16
  u16* Ob   = (u16*)(ws + (40ull << 20));   // 8 MiB: attn out
  u16* VtG  = xb;                           // transposed V (xb dead after QKV GEMM)

  cast_all<<<dim3(4096), dim3(256), 0, stream>>>(x, Wq, Wk, Wv, Wo, xb, Wb);

  // merged QKV GEMM: 128x64 tiles, BK=64, counted-vmcnt dbuf pipeline
  gemm_bt<0><<<dim3(48, 32), dim3(256), 0, stream>>>(
      xb, Wb, QKV, (size_t)(4096 * 1024), (const float*)nullptr,
      4096, 3072, 1024);

  vtrans<<<dim3(64, 16), dim3(256), 0, stream>>>(QKV + 2 * 4096 * 1024, VtG);

  attn_fused<<<dim3(16, 32), dim3(256), 0, stream>>>(
      QKV, QKV + 4096 * 1024, VtG, Ob);

  // out-proj: 128x64 tiles, BK=64, counted-vmcnt dbuf pipeline
  gemm_bt<1><<<dim3(16, 32), dim3(256), 0, stream>>>(
      Ob, Wb + 3 * 1048576, out, (size_t)0, bo, 4096, 1024, 1024);
}